// Round 1
// baseline (467.919 us; speedup 1.0000x reference)
//
#include <hip/hip_runtime.h>
#include <hip/hip_bf16.h>
#include <math.h>

__device__ __forceinline__ float leaky02(float x) { return x > 0.f ? x : 0.2f * x; }

// K1: per node n (one block of 256): h1[n][j] = sum_k x[n][k]*W1[k][j];
//     as1[n][h] = sum_c h1[n][h*32+c]*att_s[h*32+c]; same for ad1.
__global__ void k_node1(const float* __restrict__ x, const float* __restrict__ W1,
                        const float* __restrict__ att_s, const float* __restrict__ att_d,
                        float* __restrict__ h1, float* __restrict__ as1,
                        float* __restrict__ ad1, int N) {
    int n = blockIdx.x;
    int j = threadIdx.x;  // 0..255 = channel (h*32+c)
    float x0 = x[n * 3 + 0], x1 = x[n * 3 + 1], x2 = x[n * 3 + 2];
    float h = x0 * W1[j] + x1 * W1[256 + j] + x2 * W1[512 + j];
    h1[(size_t)n * 256 + j] = h;
    float vs = h * att_s[j];
    float vd = h * att_d[j];
    #pragma unroll
    for (int m = 1; m < 32; m <<= 1) {
        vs += __shfl_xor(vs, m);
        vd += __shfl_xor(vd, m);
    }
    if ((j & 31) == 0) {
        as1[n * 8 + (j >> 5)] = vs;
        ad1[n * 8 + (j >> 5)] = vd;
    }
}

__global__ void k_init_counts(int* counts, int N) {
    int t = blockIdx.x * blockDim.x + threadIdx.x;
    if (t < N) counts[t] = 1;  // self-loop
}

__global__ void k_count(const int* __restrict__ ei, int* counts, int E) {
    int t = blockIdx.x * blockDim.x + threadIdx.x;
    if (t < E) atomicAdd(&counts[ei[E + t]], 1);  // dst row
}

// single-block exclusive scan: offs[0]=0, offs[i+1]=sum(counts[0..i])
__global__ void k_scan(const int* __restrict__ counts, int* offs, int n) {
    __shared__ int temp[1024];
    __shared__ int carry_s;
    if (threadIdx.x == 0) { carry_s = 0; offs[0] = 0; }
    __syncthreads();
    for (int base = 0; base < n; base += 1024) {
        int i = base + (int)threadIdx.x;
        int v = (i < n) ? counts[i] : 0;
        temp[threadIdx.x] = v;
        __syncthreads();
        for (int off = 1; off < 1024; off <<= 1) {
            int t = (threadIdx.x >= (unsigned)off) ? temp[threadIdx.x - off] : 0;
            __syncthreads();
            temp[threadIdx.x] += t;
            __syncthreads();
        }
        int incl = temp[threadIdx.x] + carry_s;
        if (i < n) offs[i + 1] = incl;
        __syncthreads();
        if (threadIdx.x == 1023) carry_s += temp[1023];
        __syncthreads();
    }
}

__global__ void k_cursor(const int* __restrict__ offs, int* cursor, int N) {
    int t = blockIdx.x * blockDim.x + threadIdx.x;
    if (t < N) cursor[t] = offs[t];
}

__global__ void k_scatter(const int* __restrict__ ei, int* cursor, int* srcs, int E, int N) {
    int t = blockIdx.x * blockDim.x + threadIdx.x;
    if (t < E) {
        int s = ei[t], d = ei[E + t];
        int pos = atomicAdd(&cursor[d], 1);
        srcs[pos] = s;
    } else if (t < E + N) {
        int i = t - E;
        int pos = atomicAdd(&cursor[i], 1);
        srcs[pos] = i;  // self loop
    }
}

// K5: one wave per dst node. Lane owns channels [4*lane, 4*lane+3] (head = lane>>3).
// Two passes over incoming edges: segment max, then exp/sum/weighted accumulate.
// Fused: alpha-divide, +b1, ELU -> feat.
__global__ void k_agg1(const float* __restrict__ h1, const float* __restrict__ as1,
                       const float* __restrict__ ad1, const float* __restrict__ b1,
                       const int* __restrict__ offs, const int* __restrict__ srcs,
                       float* __restrict__ feat, int N) {
    int wid = threadIdx.x >> 6;
    int d = blockIdx.x * 4 + wid;
    if (d >= N) return;
    int lane = threadIdx.x & 63;
    int head = lane >> 3;
    float ad = ad1[d * 8 + head];
    int beg = offs[d], end = offs[d + 1];
    float m = -1e30f;
    for (int k = beg; k < end; ++k) {
        int s = srcs[k];
        float e = leaky02(as1[s * 8 + head] + ad);
        m = fmaxf(m, e);
    }
    float denom = 0.f, a0 = 0.f, a1 = 0.f, a2 = 0.f, a3 = 0.f;
    for (int k = beg; k < end; ++k) {
        int s = srcs[k];
        float e = leaky02(as1[s * 8 + head] + ad);
        float p = __expf(e - m);
        denom += p;
        const float4 hv = *reinterpret_cast<const float4*>(&h1[(size_t)s * 256 + lane * 4]);
        a0 += p * hv.x; a1 += p * hv.y; a2 += p * hv.z; a3 += p * hv.w;
    }
    float inv = 1.f / (denom + 1e-16f);
    int c = lane * 4;
    float r0 = a0 * inv + b1[c + 0];
    float r1 = a1 * inv + b1[c + 1];
    float r2 = a2 * inv + b1[c + 2];
    float r3 = a3 * inv + b1[c + 3];
    size_t base = (size_t)d * 256 + c;
    feat[base + 0] = r0 > 0.f ? r0 : (__expf(r0) - 1.f);
    feat[base + 1] = r1 > 0.f ? r1 : (__expf(r1) - 1.f);
    feat[base + 2] = r2 > 0.f ? r2 : (__expf(r2) - 1.f);
    feat[base + 3] = r3 > 0.f ? r3 : (__expf(r3) - 1.f);
}

// K6: one wave per node: h2[n][o] = sum_k feat[n][k]*W2[k][o], o<16;
// lane = q*16+o, q covers k in [q*64,(q+1)*64). Then as2/ad2 via shfl reduce.
__global__ void k_node2(const float* __restrict__ feat, const float* __restrict__ W2,
                        const float* __restrict__ att_s2, const float* __restrict__ att_d2,
                        float* __restrict__ h2, float* __restrict__ as2,
                        float* __restrict__ ad2, int N) {
    int wid = threadIdx.x >> 6;
    int n = blockIdx.x * 4 + wid;
    if (n >= N) return;
    int lane = threadIdx.x & 63;
    int o = lane & 15, q = lane >> 4;
    const float* fr = feat + (size_t)n * 256;
    float acc = 0.f;
    #pragma unroll 8
    for (int j = 0; j < 64; ++j) {
        int k = q * 64 + j;
        acc += fr[k] * W2[k * 16 + o];
    }
    acc += __shfl_xor(acc, 16);
    acc += __shfl_xor(acc, 32);  // all lanes now hold h2[n][o]
    if (lane < 16) h2[n * 16 + o] = acc;
    float ts = acc * att_s2[o], td = acc * att_d2[o];
    #pragma unroll
    for (int m = 1; m < 16; m <<= 1) {
        ts += __shfl_xor(ts, m);
        td += __shfl_xor(td, m);
    }
    if (lane == 0) { as2[n] = ts; ad2[n] = td; }
}

// K7: 16 lanes per dst node; lane owns one output channel o.
__global__ void k_agg2(const float* __restrict__ h2, const float* __restrict__ as2,
                       const float* __restrict__ ad2, const float* __restrict__ b2,
                       const int* __restrict__ offs, const int* __restrict__ srcs,
                       float* __restrict__ out, int N) {
    int t = blockIdx.x * blockDim.x + threadIdx.x;
    int d = t >> 4;
    if (d >= N) return;
    int o = t & 15;
    float ad = ad2[d];
    int beg = offs[d], end = offs[d + 1];
    float m = -1e30f;
    for (int k = beg; k < end; ++k) {
        float e = leaky02(as2[srcs[k]] + ad);
        m = fmaxf(m, e);
    }
    float denom = 0.f, acc = 0.f;
    for (int k = beg; k < end; ++k) {
        int s = srcs[k];
        float e = leaky02(as2[s] + ad);
        float p = __expf(e - m);
        denom += p;
        acc += p * h2[s * 16 + o];
    }
    out[d * 16 + o] = acc / (denom + 1e-16f) + b2[o];
}

extern "C" void kernel_launch(void* const* d_in, const int* in_sizes, int n_in,
                              void* d_out, int out_size, void* d_ws, size_t ws_size,
                              hipStream_t stream) {
    const float* x       = (const float*)d_in[0];
    const int*   ei      = (const int*)d_in[1];
    const float* W1      = (const float*)d_in[2];
    const float* att_s1  = (const float*)d_in[3];
    const float* att_d1  = (const float*)d_in[4];
    const float* b1      = (const float*)d_in[5];
    const float* W2      = (const float*)d_in[6];
    const float* att_s2  = (const float*)d_in[7];
    const float* att_d2  = (const float*)d_in[8];
    const float* b2      = (const float*)d_in[9];
    float* out = (float*)d_out;

    const int N = in_sizes[0] / 3;
    const int E = in_sizes[1] / 2;
    const int Etot = E + N;

    // carve workspace (16B aligned slices)
    char* w = (char*)d_ws;
    auto alloc = [&](size_t bytes) -> void* {
        void* p = (void*)w;
        w += (bytes + 15) & ~(size_t)15;
        return p;
    };
    int* counts   = (int*)alloc((size_t)N * 4);
    int* offs     = (int*)alloc((size_t)(N + 1) * 4);
    int* cursor   = (int*)alloc((size_t)N * 4);
    int* srcs     = (int*)alloc((size_t)Etot * 4);
    float* h1     = (float*)alloc((size_t)N * 256 * 4);
    float* as1    = (float*)alloc((size_t)N * 8 * 4);
    float* ad1    = (float*)alloc((size_t)N * 8 * 4);
    float* feat   = (float*)alloc((size_t)N * 256 * 4);
    float* h2     = (float*)alloc((size_t)N * 16 * 4);
    float* as2    = (float*)alloc((size_t)N * 4);
    float* ad2    = (float*)alloc((size_t)N * 4);
    (void)ws_size; (void)n_in; (void)out_size;

    const int B = 256;
    hipLaunchKernelGGL(k_node1, dim3(N), dim3(B), 0, stream,
                       x, W1, att_s1, att_d1, h1, as1, ad1, N);
    hipLaunchKernelGGL(k_init_counts, dim3((N + B - 1) / B), dim3(B), 0, stream, counts, N);
    hipLaunchKernelGGL(k_count, dim3((E + B - 1) / B), dim3(B), 0, stream, ei, counts, E);
    hipLaunchKernelGGL(k_scan, dim3(1), dim3(1024), 0, stream, counts, offs, N);
    hipLaunchKernelGGL(k_cursor, dim3((N + B - 1) / B), dim3(B), 0, stream, offs, cursor, N);
    hipLaunchKernelGGL(k_scatter, dim3((Etot + B - 1) / B), dim3(B), 0, stream,
                       ei, cursor, srcs, E, N);
    hipLaunchKernelGGL(k_agg1, dim3((N + 3) / 4), dim3(B), 0, stream,
                       h1, as1, ad1, b1, offs, srcs, feat, N);
    hipLaunchKernelGGL(k_node2, dim3((N + 3) / 4), dim3(B), 0, stream,
                       feat, W2, att_s2, att_d2, h2, as2, ad2, N);
    hipLaunchKernelGGL(k_agg2, dim3((N * 16 + B - 1) / B), dim3(B), 0, stream,
                       h2, as2, ad2, b2, offs, srcs, out, N);
}

// Round 2
// 277.517 us; speedup vs baseline: 1.6861x; 1.6861x over previous
//
#include <hip/hip_runtime.h>
#include <hip/hip_bf16.h>
#include <hip/hip_fp16.h>
#include <math.h>

__device__ __forceinline__ float leaky02(float x) { return x > 0.f ? x : 0.2f * x; }

// K1: one wave per node; lane owns channels [4*lane .. 4*lane+3].
// h1h (fp16) = x@W1; as1/ad1 per head via 8-lane shfl reduce (f32).
__global__ void k_node1(const float* __restrict__ x, const float* __restrict__ W1,
                        const float* __restrict__ att_s, const float* __restrict__ att_d,
                        __half* __restrict__ h1h, float* __restrict__ as1,
                        float* __restrict__ ad1, int N) {
    int wid = threadIdx.x >> 6;
    int n = blockIdx.x * 4 + wid;
    if (n >= N) return;
    int lane = threadIdx.x & 63;
    int c = lane * 4;
    float x0 = x[n * 3 + 0], x1 = x[n * 3 + 1], x2 = x[n * 3 + 2];
    float4 w0 = *reinterpret_cast<const float4*>(&W1[c]);
    float4 w1 = *reinterpret_cast<const float4*>(&W1[256 + c]);
    float4 w2 = *reinterpret_cast<const float4*>(&W1[512 + c]);
    float h0 = x0 * w0.x + x1 * w1.x + x2 * w2.x;
    float h1_ = x0 * w0.y + x1 * w1.y + x2 * w2.y;
    float h2_ = x0 * w0.z + x1 * w1.z + x2 * w2.z;
    float h3 = x0 * w0.w + x1 * w1.w + x2 * w2.w;
    // pack to fp16, 8B store
    __half2 p01 = __floats2half2_rn(h0, h1_);
    __half2 p23 = __floats2half2_rn(h2_, h3);
    union { __half2 h[2]; uint2 u; } pk;
    pk.h[0] = p01; pk.h[1] = p23;
    *reinterpret_cast<uint2*>(h1h + (size_t)n * 256 + c) = pk.u;
    float4 as = *reinterpret_cast<const float4*>(&att_s[c]);
    float4 ad = *reinterpret_cast<const float4*>(&att_d[c]);
    float vs = h0 * as.x + h1_ * as.y + h2_ * as.z + h3 * as.w;
    float vd = h0 * ad.x + h1_ * ad.y + h2_ * ad.z + h3 * ad.w;
    #pragma unroll
    for (int m = 1; m < 8; m <<= 1) {
        vs += __shfl_xor(vs, m);
        vd += __shfl_xor(vd, m);
    }
    if ((lane & 7) == 0) {
        as1[n * 8 + (lane >> 3)] = vs;
        ad1[n * 8 + (lane >> 3)] = vd;
    }
}

__global__ void k_init_counts(int* counts, int N) {
    int t = blockIdx.x * blockDim.x + threadIdx.x;
    if (t < N) counts[t] = 1;  // self-loop
}

__global__ void k_count(const int* __restrict__ ei, int* counts, int E) {
    int t = blockIdx.x * blockDim.x + threadIdx.x;
    if (t < E) atomicAdd(&counts[ei[E + t]], 1);  // dst row
}

// hierarchical scan: per-1024-chunk block sums
__global__ void k_bsum(const int* __restrict__ counts, int* __restrict__ bsum, int N) {
    __shared__ int wsum[4];
    int b = blockIdx.x;
    int t = threadIdx.x;
    int s = 0;
    #pragma unroll
    for (int j = 0; j < 4; ++j) {
        int i = b * 1024 + j * 256 + t;
        if (i < N) s += counts[i];
    }
    #pragma unroll
    for (int m = 1; m < 64; m <<= 1) s += __shfl_xor(s, m);
    int lane = t & 63, wid = t >> 6;
    if (lane == 0) wsum[wid] = s;
    __syncthreads();
    if (t == 0) bsum[b] = wsum[0] + wsum[1] + wsum[2] + wsum[3];
}

// exclusive scan of block sums (nb small), single wave with carry
__global__ void k_bscan(int* bsum, int nb) {
    int lane = threadIdx.x;
    int carry = 0;
    for (int base = 0; base < nb; base += 64) {
        int i = base + lane;
        int v = (i < nb) ? bsum[i] : 0;
        int incl = v;
        #pragma unroll
        for (int off = 1; off < 64; off <<= 1) {
            int tv = __shfl_up(incl, off);
            if (lane >= off) incl += tv;
        }
        if (i < nb) bsum[i] = carry + incl - v;  // exclusive
        carry += __shfl(incl, 63);
    }
}

// per-block offsets + cursor (fused). Each thread handles 4 consecutive counts.
__global__ void k_offs(const int* __restrict__ counts, const int* __restrict__ bsum,
                       int* __restrict__ offs, int* __restrict__ cursor, int N) {
    __shared__ int wsum[4];
    int b = blockIdx.x;
    int t = threadIdx.x;
    int lane = t & 63, wid = t >> 6;
    int i0 = b * 1024 + t * 4;
    int c0 = 0, c1 = 0, c2 = 0, c3 = 0;
    if (i0 + 3 < N) {
        int4 cv = *reinterpret_cast<const int4*>(&counts[i0]);
        c0 = cv.x; c1 = cv.y; c2 = cv.z; c3 = cv.w;
    } else {
        if (i0 + 0 < N) c0 = counts[i0 + 0];
        if (i0 + 1 < N) c1 = counts[i0 + 1];
        if (i0 + 2 < N) c2 = counts[i0 + 2];
        if (i0 + 3 < N) c3 = counts[i0 + 3];
    }
    int tsum = c0 + c1 + c2 + c3;
    int incl = tsum;
    #pragma unroll
    for (int off = 1; off < 64; off <<= 1) {
        int tv = __shfl_up(incl, off);
        if (lane >= off) incl += tv;
    }
    if (lane == 63) wsum[wid] = incl;
    __syncthreads();
    int woff = 0;
    for (int w = 0; w < wid; ++w) woff += wsum[w];
    int base = bsum[b] + woff + incl - tsum;  // exclusive prefix of this thread
    int p0 = base;
    int p1 = p0 + c0;
    int p2 = p1 + c1;
    int p3 = p2 + c2;
    int p4 = p3 + c3;
    if (i0 + 0 < N) { cursor[i0 + 0] = p0; offs[i0 + 1] = p1; }
    if (i0 + 1 < N) { cursor[i0 + 1] = p1; offs[i0 + 2] = p2; }
    if (i0 + 2 < N) { cursor[i0 + 2] = p2; offs[i0 + 3] = p3; }
    if (i0 + 3 < N) { cursor[i0 + 3] = p3; offs[i0 + 4] = p4; }
    if (b == 0 && t == 0) offs[0] = 0;
}

__global__ void k_scatter(const int* __restrict__ ei, int* cursor, int* srcs, int E, int N) {
    int t = blockIdx.x * blockDim.x + threadIdx.x;
    if (t < E) {
        int s = ei[t], d = ei[E + t];
        int pos = atomicAdd(&cursor[d], 1);
        srcs[pos] = s;
    } else if (t < E + N) {
        int i = t - E;
        int pos = atomicAdd(&cursor[i], 1);
        srcs[pos] = i;  // self loop
    }
}

// K5: one wave per dst node. Lane owns 4 channels (head = lane>>3).
// Single pass (softmax without max-shift: logits are O(1) here).
// srcs preloaded per 64-edge chunk, distributed via shfl.
__global__ void k_agg1(const __half* __restrict__ h1h, const float* __restrict__ as1,
                       const float* __restrict__ ad1, const float* __restrict__ b1,
                       const int* __restrict__ offs, const int* __restrict__ srcs,
                       float* __restrict__ feat, int N) {
    int wid = threadIdx.x >> 6;
    int d = blockIdx.x * 4 + wid;
    if (d >= N) return;
    int lane = threadIdx.x & 63;
    int head = lane >> 3;
    float ad = ad1[d * 8 + head];
    int beg = offs[d], end = offs[d + 1];
    float denom = 0.f, a0 = 0.f, a1 = 0.f, a2 = 0.f, a3 = 0.f;
    for (int cb = beg; cb < end; cb += 64) {
        int idx = cb + lane;
        int myS = srcs[idx < end ? idx : end - 1];
        int cnt = min(64, end - cb);
        for (int k = 0; k < cnt; ++k) {
            int s = __shfl(myS, k);
            float e = leaky02(as1[s * 8 + head] + ad);
            float p = __expf(e);
            denom += p;
            uint2 raw = *reinterpret_cast<const uint2*>(h1h + (size_t)s * 256 + lane * 4);
            union { unsigned u; __half2 h; } u0, u1;
            u0.u = raw.x; u1.u = raw.y;
            float2 f01 = __half22float2(u0.h);
            float2 f23 = __half22float2(u1.h);
            a0 += p * f01.x; a1 += p * f01.y; a2 += p * f23.x; a3 += p * f23.y;
        }
    }
    float inv = 1.f / (denom + 1e-16f);
    int c = lane * 4;
    float r0 = a0 * inv + b1[c + 0];
    float r1 = a1 * inv + b1[c + 1];
    float r2 = a2 * inv + b1[c + 2];
    float r3 = a3 * inv + b1[c + 3];
    size_t base = (size_t)d * 256 + c;
    feat[base + 0] = r0 > 0.f ? r0 : (__expf(r0) - 1.f);
    feat[base + 1] = r1 > 0.f ? r1 : (__expf(r1) - 1.f);
    feat[base + 2] = r2 > 0.f ? r2 : (__expf(r2) - 1.f);
    feat[base + 3] = r3 > 0.f ? r3 : (__expf(r3) - 1.f);
}

// K6: one wave per node: h2[n][o] = sum_k feat[n][k]*W2[k][o], o<16.
__global__ void k_node2(const float* __restrict__ feat, const float* __restrict__ W2,
                        const float* __restrict__ att_s2, const float* __restrict__ att_d2,
                        float* __restrict__ h2, float* __restrict__ as2,
                        float* __restrict__ ad2, int N) {
    int wid = threadIdx.x >> 6;
    int n = blockIdx.x * 4 + wid;
    if (n >= N) return;
    int lane = threadIdx.x & 63;
    int o = lane & 15, q = lane >> 4;
    const float* fr = feat + (size_t)n * 256;
    float acc = 0.f;
    #pragma unroll 8
    for (int j = 0; j < 64; ++j) {
        int k = q * 64 + j;
        acc += fr[k] * W2[k * 16 + o];
    }
    acc += __shfl_xor(acc, 16);
    acc += __shfl_xor(acc, 32);  // all lanes hold h2[n][o]
    if (lane < 16) h2[n * 16 + o] = acc;
    float ts = acc * att_s2[o], td = acc * att_d2[o];
    #pragma unroll
    for (int m = 1; m < 16; m <<= 1) {
        ts += __shfl_xor(ts, m);
        td += __shfl_xor(td, m);
    }
    if (lane == 0) { as2[n] = ts; ad2[n] = td; }
}

// K7: 16 lanes per dst node; lane owns one output channel. Single pass.
__global__ void k_agg2(const float* __restrict__ h2, const float* __restrict__ as2,
                       const float* __restrict__ ad2, const float* __restrict__ b2,
                       const int* __restrict__ offs, const int* __restrict__ srcs,
                       float* __restrict__ out, int N) {
    int t = blockIdx.x * blockDim.x + threadIdx.x;
    int d = t >> 4;
    if (d >= N) return;
    int o = t & 15;
    float ad = ad2[d];
    int beg = offs[d], end = offs[d + 1];
    float denom = 0.f, acc = 0.f;
    for (int k = beg; k < end; ++k) {
        int s = srcs[k];
        float e = leaky02(as2[s] + ad);
        float p = __expf(e);
        denom += p;
        acc += p * h2[s * 16 + o];
    }
    out[d * 16 + o] = acc / (denom + 1e-16f) + b2[o];
}

extern "C" void kernel_launch(void* const* d_in, const int* in_sizes, int n_in,
                              void* d_out, int out_size, void* d_ws, size_t ws_size,
                              hipStream_t stream) {
    const float* x       = (const float*)d_in[0];
    const int*   ei      = (const int*)d_in[1];
    const float* W1      = (const float*)d_in[2];
    const float* att_s1  = (const float*)d_in[3];
    const float* att_d1  = (const float*)d_in[4];
    const float* b1      = (const float*)d_in[5];
    const float* W2      = (const float*)d_in[6];
    const float* att_s2  = (const float*)d_in[7];
    const float* att_d2  = (const float*)d_in[8];
    const float* b2      = (const float*)d_in[9];
    float* out = (float*)d_out;

    const int N = in_sizes[0] / 3;
    const int E = in_sizes[1] / 2;
    const int Etot = E + N;
    const int NB = (N + 1023) / 1024;  // scan blocks

    // carve workspace (16B aligned slices)
    char* w = (char*)d_ws;
    auto alloc = [&](size_t bytes) -> void* {
        void* p = (void*)w;
        w += (bytes + 15) & ~(size_t)15;
        return p;
    };
    int* counts   = (int*)alloc((size_t)N * 4);
    int* offs     = (int*)alloc((size_t)(N + 1) * 4);
    int* cursor   = (int*)alloc((size_t)N * 4);
    int* srcs     = (int*)alloc((size_t)Etot * 4);
    int* bsum     = (int*)alloc((size_t)(NB + 1) * 4);
    __half* h1h   = (__half*)alloc((size_t)N * 256 * 2);
    float* as1    = (float*)alloc((size_t)N * 8 * 4);
    float* ad1    = (float*)alloc((size_t)N * 8 * 4);
    float* feat   = (float*)alloc((size_t)N * 256 * 4);
    float* h2     = (float*)alloc((size_t)N * 16 * 4);
    float* as2    = (float*)alloc((size_t)N * 4);
    float* ad2    = (float*)alloc((size_t)N * 4);
    (void)ws_size; (void)n_in; (void)out_size;

    const int B = 256;
    hipLaunchKernelGGL(k_node1, dim3((N + 3) / 4), dim3(B), 0, stream,
                       x, W1, att_s1, att_d1, h1h, as1, ad1, N);
    hipLaunchKernelGGL(k_init_counts, dim3((N + B - 1) / B), dim3(B), 0, stream, counts, N);
    hipLaunchKernelGGL(k_count, dim3((E + B - 1) / B), dim3(B), 0, stream, ei, counts, E);
    hipLaunchKernelGGL(k_bsum, dim3(NB), dim3(B), 0, stream, counts, bsum, N);
    hipLaunchKernelGGL(k_bscan, dim3(1), dim3(64), 0, stream, bsum, NB);
    hipLaunchKernelGGL(k_offs, dim3(NB), dim3(B), 0, stream, counts, bsum, offs, cursor, N);
    hipLaunchKernelGGL(k_scatter, dim3((Etot + B - 1) / B), dim3(B), 0, stream,
                       ei, cursor, srcs, E, N);
    hipLaunchKernelGGL(k_agg1, dim3((N + 3) / 4), dim3(B), 0, stream,
                       h1h, as1, ad1, b1, offs, srcs, feat, N);
    hipLaunchKernelGGL(k_node2, dim3((N + 3) / 4), dim3(B), 0, stream,
                       feat, W2, att_s2, att_d2, h2, as2, ad2, N);
    hipLaunchKernelGGL(k_agg2, dim3((N * 16 + B - 1) / B), dim3(B), 0, stream,
                       h2, as2, ad2, b2, offs, srcs, out, N);
}

// Round 4
// 254.689 us; speedup vs baseline: 1.8372x; 1.0896x over previous
//
#include <hip/hip_runtime.h>
#include <hip/hip_bf16.h>
#include <hip/hip_fp16.h>
#include <math.h>

__device__ __forceinline__ float leaky02(float x) { return x > 0.f ? x : 0.2f * x; }

// K1: one wave per node; lane owns channels [4*lane .. 4*lane+3].
// h1h (fp16) = x@W1; as1/ad1 (f32) per head via 8-lane shfl reduce.
__global__ void k_node1(const float* __restrict__ x, const float* __restrict__ W1,
                        const float* __restrict__ att_s, const float* __restrict__ att_d,
                        __half* __restrict__ h1h, float* __restrict__ as1,
                        float* __restrict__ ad1, int N) {
    int wid = threadIdx.x >> 6;
    int n = blockIdx.x * 4 + wid;
    if (n >= N) return;
    int lane = threadIdx.x & 63;
    int c = lane * 4;
    float x0 = x[n * 3 + 0], x1 = x[n * 3 + 1], x2 = x[n * 3 + 2];
    float4 w0 = *reinterpret_cast<const float4*>(&W1[c]);
    float4 w1 = *reinterpret_cast<const float4*>(&W1[256 + c]);
    float4 w2 = *reinterpret_cast<const float4*>(&W1[512 + c]);
    float h0 = x0 * w0.x + x1 * w1.x + x2 * w2.x;
    float h1_ = x0 * w0.y + x1 * w1.y + x2 * w2.y;
    float h2_ = x0 * w0.z + x1 * w1.z + x2 * w2.z;
    float h3 = x0 * w0.w + x1 * w1.w + x2 * w2.w;
    union { __half2 h[2]; uint2 u; } pk;
    pk.h[0] = __floats2half2_rn(h0, h1_);
    pk.h[1] = __floats2half2_rn(h2_, h3);
    *reinterpret_cast<uint2*>(h1h + (size_t)n * 256 + c) = pk.u;
    float4 as = *reinterpret_cast<const float4*>(&att_s[c]);
    float4 ad = *reinterpret_cast<const float4*>(&att_d[c]);
    float vs = h0 * as.x + h1_ * as.y + h2_ * as.z + h3 * as.w;
    float vd = h0 * ad.x + h1_ * ad.y + h2_ * ad.z + h3 * ad.w;
    #pragma unroll
    for (int m = 1; m < 8; m <<= 1) {
        vs += __shfl_xor(vs, m);
        vd += __shfl_xor(vd, m);
    }
    if ((lane & 7) == 0) {
        as1[n * 8 + (lane >> 3)] = vs;
        ad1[n * 8 + (lane >> 3)] = vd;
    }
}

__global__ void k_init_counts(int* counts, int N) {
    int t = blockIdx.x * blockDim.x + threadIdx.x;
    if (t < N) counts[t] = 1;  // self-loop
}

__global__ void k_count(const int* __restrict__ ei, int* counts, int E) {
    int t = blockIdx.x * blockDim.x + threadIdx.x;
    if (t < E) atomicAdd(&counts[ei[E + t]], 1);  // dst row
}

// hierarchical scan: per-1024-chunk block sums
__global__ void k_bsum(const int* __restrict__ counts, int* __restrict__ bsum, int N) {
    __shared__ int wsum[4];
    int b = blockIdx.x;
    int t = threadIdx.x;
    int s = 0;
    #pragma unroll
    for (int j = 0; j < 4; ++j) {
        int i = b * 1024 + j * 256 + t;
        if (i < N) s += counts[i];
    }
    #pragma unroll
    for (int m = 1; m < 64; m <<= 1) s += __shfl_xor(s, m);
    int lane = t & 63, wid = t >> 6;
    if (lane == 0) wsum[wid] = s;
    __syncthreads();
    if (t == 0) bsum[b] = wsum[0] + wsum[1] + wsum[2] + wsum[3];
}

// exclusive scan of block sums (nb small), single wave with carry
__global__ void k_bscan(int* bsum, int nb) {
    int lane = threadIdx.x;
    int carry = 0;
    for (int base = 0; base < nb; base += 64) {
        int i = base + lane;
        int v = (i < nb) ? bsum[i] : 0;
        int incl = v;
        #pragma unroll
        for (int off = 1; off < 64; off <<= 1) {
            int tv = __shfl_up(incl, off);
            if (lane >= off) incl += tv;
        }
        if (i < nb) bsum[i] = carry + incl - v;  // exclusive
        carry += __shfl(incl, 63);
    }
}

// per-block offsets + cursor (fused). Each thread handles 4 consecutive counts.
__global__ void k_offs(const int* __restrict__ counts, const int* __restrict__ bsum,
                       int* __restrict__ offs, int* __restrict__ cursor, int N) {
    __shared__ int wsum[4];
    int b = blockIdx.x;
    int t = threadIdx.x;
    int lane = t & 63, wid = t >> 6;
    int i0 = b * 1024 + t * 4;
    int c0 = 0, c1 = 0, c2 = 0, c3 = 0;
    if (i0 + 3 < N) {
        int4 cv = *reinterpret_cast<const int4*>(&counts[i0]);
        c0 = cv.x; c1 = cv.y; c2 = cv.z; c3 = cv.w;
    } else {
        if (i0 + 0 < N) c0 = counts[i0 + 0];
        if (i0 + 1 < N) c1 = counts[i0 + 1];
        if (i0 + 2 < N) c2 = counts[i0 + 2];
        if (i0 + 3 < N) c3 = counts[i0 + 3];
    }
    int tsum = c0 + c1 + c2 + c3;
    int incl = tsum;
    #pragma unroll
    for (int off = 1; off < 64; off <<= 1) {
        int tv = __shfl_up(incl, off);
        if (lane >= off) incl += tv;
    }
    if (lane == 63) wsum[wid] = incl;
    __syncthreads();
    int woff = 0;
    for (int w = 0; w < wid; ++w) woff += wsum[w];
    int base = bsum[b] + woff + incl - tsum;  // exclusive prefix of this thread
    int p0 = base;
    int p1 = p0 + c0;
    int p2 = p1 + c1;
    int p3 = p2 + c2;
    int p4 = p3 + c3;
    if (i0 + 0 < N) { cursor[i0 + 0] = p0; offs[i0 + 1] = p1; }
    if (i0 + 1 < N) { cursor[i0 + 1] = p1; offs[i0 + 2] = p2; }
    if (i0 + 2 < N) { cursor[i0 + 2] = p2; offs[i0 + 3] = p3; }
    if (i0 + 3 < N) { cursor[i0 + 3] = p3; offs[i0 + 4] = p4; }
    if (b == 0 && t == 0) offs[0] = 0;
}

__global__ void k_scatter(const int* __restrict__ ei, int* cursor, int* srcs, int E, int N) {
    int t = blockIdx.x * blockDim.x + threadIdx.x;
    if (t < E) {
        int s = ei[t], d = ei[E + t];
        int pos = atomicAdd(&cursor[d], 1);
        srcs[pos] = s;
    } else if (t < E + N) {
        int i = t - E;
        int pos = atomicAdd(&cursor[i], 1);
        srcs[pos] = i;  // self loop
    }
}

// K5: one wave per dst node. Lane owns 4 channels (head = lane>>3).
// Single pass (softmax without max-shift: logits are O(1) here).
// srcs preloaded per 64-edge chunk, distributed via shfl (cnt wave-uniform
// so the shfl loop is convergent). Output fp16.
__global__ void k_agg1(const __half* __restrict__ h1h, const float* __restrict__ as1,
                       const float* __restrict__ ad1, const float* __restrict__ b1,
                       const int* __restrict__ offs, const int* __restrict__ srcs,
                       __half* __restrict__ feath, int N) {
    int wid = threadIdx.x >> 6;
    int d = blockIdx.x * 4 + wid;
    if (d >= N) return;
    int lane = threadIdx.x & 63;
    int head = lane >> 3;
    float ad = ad1[d * 8 + head];
    int beg = offs[d], end = offs[d + 1];
    float denom = 0.f, a0 = 0.f, a1 = 0.f, a2 = 0.f, a3 = 0.f;
    for (int cb = beg; cb < end; cb += 64) {
        int idx = cb + lane;
        int myS = srcs[idx < end ? idx : end - 1];
        int cnt = min(64, end - cb);
        #pragma unroll 4
        for (int k = 0; k < cnt; ++k) {
            int s = __shfl(myS, k);
            float e = leaky02(as1[s * 8 + head] + ad);
            float p = __expf(e);
            denom += p;
            uint2 raw = *reinterpret_cast<const uint2*>(h1h + (size_t)s * 256 + lane * 4);
            union { unsigned u; __half2 h; } u0, u1;
            u0.u = raw.x; u1.u = raw.y;
            float2 f01 = __half22float2(u0.h);
            float2 f23 = __half22float2(u1.h);
            a0 += p * f01.x; a1 += p * f01.y; a2 += p * f23.x; a3 += p * f23.y;
        }
    }
    float inv = 1.f / (denom + 1e-16f);
    int c = lane * 4;
    float4 bv = *reinterpret_cast<const float4*>(&b1[c]);
    float r0 = a0 * inv + bv.x;
    float r1 = a1 * inv + bv.y;
    float r2 = a2 * inv + bv.z;
    float r3 = a3 * inv + bv.w;
    r0 = r0 > 0.f ? r0 : (__expf(r0) - 1.f);
    r1 = r1 > 0.f ? r1 : (__expf(r1) - 1.f);
    r2 = r2 > 0.f ? r2 : (__expf(r2) - 1.f);
    r3 = r3 > 0.f ? r3 : (__expf(r3) - 1.f);
    union { __half2 h[2]; uint2 u; } pk;
    pk.h[0] = __floats2half2_rn(r0, r1);
    pk.h[1] = __floats2half2_rn(r2, r3);
    *reinterpret_cast<uint2*>(feath + (size_t)d * 256 + c) = pk.u;
}

// K6: one wave per node: h2[n][o] = sum_k feat[n][k]*W2[k][o], o<16.
// Lane q=lane>>4 reads its 64-k slice as uint4 (8 fp16 / 16B per load).
__global__ void k_node2(const __half* __restrict__ feath, const float* __restrict__ W2,
                        const float* __restrict__ att_s2, const float* __restrict__ att_d2,
                        __half* __restrict__ h2h, float* __restrict__ as2,
                        float* __restrict__ ad2, int N) {
    int wid = threadIdx.x >> 6;
    int n = blockIdx.x * 4 + wid;
    if (n >= N) return;
    int lane = threadIdx.x & 63;
    int o = lane & 15, q = lane >> 4;
    const __half* fr = feath + (size_t)n * 256 + q * 64;
    const float* w = W2 + (q * 64) * 16 + o;
    float acc = 0.f;
    #pragma unroll
    for (int jj = 0; jj < 8; ++jj) {
        union { uint4 u; __half2 h[4]; } v;
        v.u = *reinterpret_cast<const uint4*>(fr + jj * 8);
        #pragma unroll
        for (int t = 0; t < 4; ++t) {
            float2 f = __half22float2(v.h[t]);
            acc += f.x * w[(jj * 8 + t * 2 + 0) * 16];
            acc += f.y * w[(jj * 8 + t * 2 + 1) * 16];
        }
    }
    acc += __shfl_xor(acc, 16);
    acc += __shfl_xor(acc, 32);  // all lanes hold h2[n][o]
    if (lane < 16) h2h[n * 16 + o] = __float2half(acc);
    float ts = acc * att_s2[o], td = acc * att_d2[o];
    #pragma unroll
    for (int m = 1; m < 16; m <<= 1) {
        ts += __shfl_xor(ts, m);
        td += __shfl_xor(td, m);
    }
    if (lane == 0) { as2[n] = ts; ad2[n] = td; }
}

// K7: one wave per dst. lane = eg*4+cl: 16 edge-groups x 4 lanes owning
// 4 channels each (8B h2h loads). All lanes execute every shfl (convergent);
// only the accumulate is predicated — shfl-from-inactive-lane is UB.
__global__ void k_agg2(const __half* __restrict__ h2h, const float* __restrict__ as2,
                       const float* __restrict__ ad2, const float* __restrict__ b2,
                       const int* __restrict__ offs, const int* __restrict__ srcs,
                       float* __restrict__ out, int N) {
    int wid = threadIdx.x >> 6;
    int d = blockIdx.x * 4 + wid;
    if (d >= N) return;
    int lane = threadIdx.x & 63;
    int cl = lane & 3, eg = lane >> 2;
    float ad = ad2[d];
    int beg = offs[d], end = offs[d + 1];
    float denom = 0.f, a0 = 0.f, a1 = 0.f, a2 = 0.f, a3 = 0.f;
    for (int cb = beg; cb < end; cb += 64) {
        int idx = cb + lane;
        int myS = srcs[idx < end ? idx : end - 1];
        #pragma unroll
        for (int cc = 0; cc < 4; ++cc) {
            int s = __shfl(myS, cc * 16 + eg);   // convergent: all 64 lanes
            int epos = cb + cc * 16 + eg;
            if (epos < end) {
                float e = leaky02(as2[s] + ad);
                float p = __expf(e);
                denom += p;
                uint2 raw = *reinterpret_cast<const uint2*>(h2h + (size_t)s * 16 + cl * 4);
                union { unsigned u; __half2 h; } u0, u1;
                u0.u = raw.x; u1.u = raw.y;
                float2 f01 = __half22float2(u0.h);
                float2 f23 = __half22float2(u1.h);
                a0 += p * f01.x; a1 += p * f01.y; a2 += p * f23.x; a3 += p * f23.y;
            }
        }
    }
    #pragma unroll
    for (int m = 4; m < 64; m <<= 1) {
        denom += __shfl_xor(denom, m);
        a0 += __shfl_xor(a0, m);
        a1 += __shfl_xor(a1, m);
        a2 += __shfl_xor(a2, m);
        a3 += __shfl_xor(a3, m);
    }
    if (eg == 0) {
        float inv = 1.f / (denom + 1e-16f);
        int c = cl * 4;
        float4 r;
        r.x = a0 * inv + b2[c + 0];
        r.y = a1 * inv + b2[c + 1];
        r.z = a2 * inv + b2[c + 2];
        r.w = a3 * inv + b2[c + 3];
        *reinterpret_cast<float4*>(&out[d * 16 + c]) = r;
    }
}

extern "C" void kernel_launch(void* const* d_in, const int* in_sizes, int n_in,
                              void* d_out, int out_size, void* d_ws, size_t ws_size,
                              hipStream_t stream) {
    const float* x       = (const float*)d_in[0];
    const int*   ei      = (const int*)d_in[1];
    const float* W1      = (const float*)d_in[2];
    const float* att_s1  = (const float*)d_in[3];
    const float* att_d1  = (const float*)d_in[4];
    const float* b1      = (const float*)d_in[5];
    const float* W2      = (const float*)d_in[6];
    const float* att_s2  = (const float*)d_in[7];
    const float* att_d2  = (const float*)d_in[8];
    const float* b2      = (const float*)d_in[9];
    float* out = (float*)d_out;

    const int N = in_sizes[0] / 3;
    const int E = in_sizes[1] / 2;
    const int Etot = E + N;
    const int NB = (N + 1023) / 1024;  // scan blocks

    // carve workspace (16B aligned slices)
    char* w = (char*)d_ws;
    auto alloc = [&](size_t bytes) -> void* {
        void* p = (void*)w;
        w += (bytes + 15) & ~(size_t)15;
        return p;
    };
    int* counts   = (int*)alloc((size_t)N * 4);
    int* offs     = (int*)alloc((size_t)(N + 1) * 4);
    int* cursor   = (int*)alloc((size_t)N * 4);
    int* srcs     = (int*)alloc((size_t)Etot * 4);
    int* bsum     = (int*)alloc((size_t)(NB + 1) * 4);
    __half* h1h   = (__half*)alloc((size_t)N * 256 * 2);
    float* as1    = (float*)alloc((size_t)N * 8 * 4);
    float* ad1    = (float*)alloc((size_t)N * 8 * 4);
    __half* feath = (__half*)alloc((size_t)N * 256 * 2);
    __half* h2h   = (__half*)alloc((size_t)N * 16 * 2);
    float* as2    = (float*)alloc((size_t)N * 4);
    float* ad2    = (float*)alloc((size_t)N * 4);
    (void)ws_size; (void)n_in; (void)out_size;

    const int B = 256;
    hipLaunchKernelGGL(k_node1, dim3((N + 3) / 4), dim3(B), 0, stream,
                       x, W1, att_s1, att_d1, h1h, as1, ad1, N);
    hipLaunchKernelGGL(k_init_counts, dim3((N + B - 1) / B), dim3(B), 0, stream, counts, N);
    hipLaunchKernelGGL(k_count, dim3((E + B - 1) / B), dim3(B), 0, stream, ei, counts, E);
    hipLaunchKernelGGL(k_bsum, dim3(NB), dim3(B), 0, stream, counts, bsum, N);
    hipLaunchKernelGGL(k_bscan, dim3(1), dim3(64), 0, stream, bsum, NB);
    hipLaunchKernelGGL(k_offs, dim3(NB), dim3(B), 0, stream, counts, bsum, offs, cursor, N);
    hipLaunchKernelGGL(k_scatter, dim3((Etot + B - 1) / B), dim3(B), 0, stream,
                       ei, cursor, srcs, E, N);
    hipLaunchKernelGGL(k_agg1, dim3((N + 3) / 4), dim3(B), 0, stream,
                       h1h, as1, ad1, b1, offs, srcs, feath, N);
    hipLaunchKernelGGL(k_node2, dim3((N + 3) / 4), dim3(B), 0, stream,
                       feath, W2, att_s2, att_d2, h2h, as2, ad2, N);
    hipLaunchKernelGGL(k_agg2, dim3((N + 3) / 4), dim3(B), 0, stream,
                       h2h, as2, ad2, b2, offs, srcs, out, N);
}